// Round 24
// baseline (58.317 us; speedup 1.0000x reference)
//
#include <hip/hip_runtime.h>

#define B_ 64
#define T_ 1000
#define C_ 128
#define L_ 100
#define BLANK 127     // C-1
#define LN2F 0.69314718055994530942f
#define PH 32
#define FSTRIDE 1024  // 64 lanes * 16B (q1,q3 f64 pair)
#define BUFSZ32 (PH * FSTRIDE)   // 32 KB per buffer; 4 buffers = 128 KB

__device__ __forceinline__ float flog2(float x) { return __builtin_amdgcn_logf(x); }
__device__ __forceinline__ float frcp(float x)  { return __builtin_amdgcn_rcpf(x); }

#define DPP_ROW_SHR1   0x111
#define DPP_ROW_SHR2   0x112
#define DPP_ROW_SHR4   0x114
#define DPP_ROW_SHR8   0x118
#define DPP_WAVE_SHR1  0x138   // lane i <- lane i-1 (validated R8)
#define DPP_WAVE_SHL1  0x130   // lane i <- lane i+1 (validated R15/R16)

template <int CTRL>
__device__ __forceinline__ int dpp_mov(int src) {
    return __builtin_amdgcn_update_dpp(0, src, CTRL, 0xF, 0xF, false);
}

// R24: 64 blocks; ONE consumer wave runs BOTH direction chains interleaved
// (fwd a-regs via STEPQ, bwd g-regs via STEPB) -- two independent f64
// dependency chains fill each other's stall slots. Producers: wv1-2 fwd,
// wv3-4 bwd (R20's validated fill8). alpha_H and beta_H end in the same
// wave -> in-wave dot product; combine kernel + d_ws round trip deleted.
__global__ __launch_bounds__(320, 1) void ctc_fused_kernel(
    const int* __restrict__ y_true, const float* __restrict__ y_pred,
    const int* __restrict__ in_len, const int* __restrict__ lab_len,
    float* __restrict__ out)
{
    const int bb  = blockIdx.x;
    const int tid = threadIdx.x;
    const int l   = tid & 63;
    const int wv  = tid >> 6;   // 0 consumer; 1,2 fwd producers; 3,4 bwd

    __shared__ __align__(16) char ldsb[4 * BUFSZ32];   // [fwd e/o | bwd e/o]
    __shared__ float lgs[2][4];

    const int* yb = y_true + bb * L_;
    const int k1 = min(2 * l, L_ - 1);
    const int k3 = min(2 * l + 1, L_ - 1);
    const int e1 = yb[k1];
    const int e3 = yb[k3];
    const double m1 = (k1 == 0 || e1 != yb[k1 - 1]) ? 1.0 : 0.0;
    const double m3 = (e3 != yb[k3 - 1]) ? 1.0 : 0.0;
    const int k1n = min(2 * l + 2, L_ - 1);
    const double m1n = (yb[k1n] != yb[k1n - 1]) ? 1.0 : 0.0;

    const int Teff = min(T_, in_len[bb]);
    const int N    = Teff - 1;
    const int Hf   = (N + 1) >> 1;       // fwd steps t=1..Hf
    const int Hb   = N - Hf;             // bwd steps t=N..Hf+1  (Hb<=Hf)
    const int P    = (Hf + 31) >> 5;
    const float* rowb = y_pred + (size_t)bb * T_ * C_;

    double a0 = 0.0, a1 = 0.0, a2 = 0.0, a3 = 0.0;   // fwd alpha
    double g0 = 0.0, g1 = 0.0, g2 = 0.0, g3 = 0.0;   // bwd beta
    double Lsum = 0.0;
    int E = 0;

    // ---- producer: fill one 8-frame chunk (dirB selects direction) ----
    auto fill8 = [&](bool dirB, int phf, int cs, float& lgacc) {
        char* bbw = ldsb + ((dirB ? 2 : 0) + (phf & 1)) * BUFSZ32;
        const int kb_ = phf * PH + cs;
        float g10,g30,gb0, g11,g31,gb1, g12,g32,gb2, g13,g33,gb3,
              g14,g34,gb4, g15,g35,gb5, g16,g36,gb6, g17,g37,gb7;
        int t0_,t1_,t2_,t3_,t4_,t5_,t6_,t7_;
#define FR(i_) (dirB ? (N - (kb_ + i_)) : (1 + kb_ + i_))
        t0_=FR(0); t1_=FR(1); t2_=FR(2); t3_=FR(3);
        t4_=FR(4); t5_=FR(5); t6_=FR(6); t7_=FR(7);
#undef FR
        {
            const float* r_;
            r_ = rowb + (size_t)min(max(t0_,1),N) * C_; g10=r_[e1]; g30=r_[e3]; gb0=r_[BLANK];
            r_ = rowb + (size_t)min(max(t1_,1),N) * C_; g11=r_[e1]; g31=r_[e3]; gb1=r_[BLANK];
            r_ = rowb + (size_t)min(max(t2_,1),N) * C_; g12=r_[e1]; g32=r_[e3]; gb2=r_[BLANK];
            r_ = rowb + (size_t)min(max(t3_,1),N) * C_; g13=r_[e1]; g33=r_[e3]; gb3=r_[BLANK];
            r_ = rowb + (size_t)min(max(t4_,1),N) * C_; g14=r_[e1]; g34=r_[e3]; gb4=r_[BLANK];
            r_ = rowb + (size_t)min(max(t5_,1),N) * C_; g15=r_[e1]; g35=r_[e3]; gb5=r_[BLANK];
            r_ = rowb + (size_t)min(max(t6_,1),N) * C_; g16=r_[e1]; g36=r_[e3]; gb6=r_[BLANK];
            r_ = rowb + (size_t)min(max(t7_,1),N) * C_; g17=r_[e1]; g37=r_[e3]; gb7=r_[BLANK];
        }
        __builtin_amdgcn_sched_barrier(0);   // all loads before compute/writes
#define PWR(i_, T_V, G1, G3, GB) { \
        float rb_ = GB + 1e-7f; \
        float rc_ = frcp(rb_); \
        char* q_ = bbw + (cs + i_) * FSTRIDE; \
        *(double2*)(q_ + 16 * l) = make_double2((double)((G1 + 1e-7f) * rc_), \
                                                 (double)((G3 + 1e-7f) * rc_)); \
        bool ok_ = dirB ? (T_V >= Hf + 1 && T_V <= N) : (T_V >= 1 && T_V <= Hf); \
        lgacc += ok_ ? flog2(rb_) : 0.f; }
        PWR(0, t0_, g10, g30, gb0); PWR(1, t1_, g11, g31, gb1);
        PWR(2, t2_, g12, g32, gb2); PWR(3, t3_, g13, g33, gb3);
        PWR(4, t4_, g14, g34, gb4); PWR(5, t5_, g15, g35, gb5);
        PWR(6, t6_, g16, g36, gb6); PWR(7, t7_, g17, g37, gb7);
#undef PWR
    };

    auto fill_phase = [&](int phf) {
        const bool dirB = (wv >= 3);
        const int  cs0  = ((wv - 1) & 1) * 16;
        float lg_ = 0.f;
        fill8(dirB, phf, cs0,     lg_);
        fill8(dirB, phf, cs0 + 8, lg_);
        if (l == 0) lgs[phf & 1][wv - 1] = lg_;
    };

#define DECLF(Pr) double Pr##q1, Pr##q3
#define DECLB(Pr) double Pr##q1, Pr##q3, Pr##q1n
#define LDF(Pr, fi_) { \
    double2 v_ = *(const double2*)(baseF_ + (fi_) * FSTRIDE + 16 * l); \
    Pr##q1 = v_.x; Pr##q3 = v_.y; }
#define LDFB(Pr, fi_) { \
    double2 v_ = *(const double2*)(baseB_ + (fi_) * FSTRIDE + 16 * l); \
    Pr##q1 = v_.x; Pr##q3 = v_.y; \
    Pr##q1n = *(const double*)(baseB_ + (fi_) * FSTRIDE + 16 * ((l + 1) & 63)); }

#define STEPQ(Pr) { \
    int slo_ = dpp_mov<DPP_WAVE_SHR1>(__double2loint(a3)); \
    int shi_ = dpp_mov<DPP_WAVE_SHR1>(__double2hiint(a3)); \
    double pm1_ = __hiloint2double(shi_, slo_); \
    double n0_ = a0 + pm1_; \
    double n1_ = (a1 + a0 + m1 * pm1_) * Pr##q1; \
    double n2_ = a2 + a1; \
    double n3_ = (a3 + a2 + m3 * a1) * Pr##q3; \
    a0 = n0_; a1 = n1_; a2 = n2_; a3 = n3_; }

#define STEPB(Pr) { \
    int n0lo_ = dpp_mov<DPP_WAVE_SHL1>(__double2loint(g0)); \
    int n0hi_ = dpp_mov<DPP_WAVE_SHL1>(__double2hiint(g0)); \
    int n1lo_ = dpp_mov<DPP_WAVE_SHL1>(__double2loint(g1)); \
    int n1hi_ = dpp_mov<DPP_WAVE_SHL1>(__double2hiint(g1)); \
    double b0n_ = __hiloint2double(n0hi_, n0lo_); \
    double b1n_ = __hiloint2double(n1hi_, n1lo_); \
    double c1_ = g1 * Pr##q1; \
    double c3_ = g3 * Pr##q3; \
    double c1n_ = b1n_ * Pr##q1n; \
    double n0_ = g0 + c1_; \
    double n1_ = c1_ + g2 + m3 * c3_; \
    double n2_ = g2 + c3_; \
    double n3_ = c3_ + b0n_ + m1n * c1n_; \
    g0 = n0_; g1 = n1_; g2 = n2_; g3 = n3_; }

#define DPPMAX(u_, ctrl_) { unsigned t_ = (unsigned)dpp_mov<ctrl_>((int)(u_)); \
    u_ = max(u_, t_); }
#define RESCALE4(x0,x1,x2,x3) { \
    unsigned u_ = max(max((unsigned)__double2hiint(x0), (unsigned)__double2hiint(x1)), \
                      max((unsigned)__double2hiint(x2), (unsigned)__double2hiint(x3))); \
    DPPMAX(u_, DPP_ROW_SHR1); \
    DPPMAX(u_, DPP_ROW_SHR2); \
    DPPMAX(u_, DPP_ROW_SHR4); \
    DPPMAX(u_, DPP_ROW_SHR8); \
    unsigned g_ = max(max((unsigned)__builtin_amdgcn_readlane((int)u_, 15), \
                          (unsigned)__builtin_amdgcn_readlane((int)u_, 31)), \
                      max((unsigned)__builtin_amdgcn_readlane((int)u_, 47), \
                          (unsigned)__builtin_amdgcn_readlane((int)u_, 63))); \
    int kk_ = (int)(g_ >> 20); \
    if (kk_ > 0) { \
        double f_ = __hiloint2double((2046 - kk_) << 20, 0); \
        x0 *= f_; x1 *= f_; x2 *= f_; x3 *= f_; \
        E += kk_ - 1023; } }
#define RESCALE2() { RESCALE4(a0,a1,a2,a3); RESCALE4(g0,g1,g2,g3); }

// dual 16-step half-body: 4-slot groups, fwd+bwd interleaved
#define H16(o_) { \
    DECLF(A0); DECLF(A1); DECLF(A2); DECLF(A3); \
    DECLB(C0); DECLB(C1); DECLB(C2); DECLB(C3); \
    DECLF(B0); DECLF(B1); DECLF(B2); DECLF(B3); \
    DECLB(D0); DECLB(D1); DECLB(D2); DECLB(D3); \
    LDF(A0,(o_)); LDF(A1,(o_)+1); LDF(A2,(o_)+2); LDF(A3,(o_)+3); \
    LDFB(C0,(o_)); LDFB(C1,(o_)+1); LDFB(C2,(o_)+2); LDFB(C3,(o_)+3); \
    LDF(B0,(o_)+4); LDF(B1,(o_)+5); LDF(B2,(o_)+6); LDF(B3,(o_)+7); \
    LDFB(D0,(o_)+4); LDFB(D1,(o_)+5); LDFB(D2,(o_)+6); LDFB(D3,(o_)+7); \
    STEPQ(A0); STEPB(C0); STEPQ(A1); STEPB(C1); \
    STEPQ(A2); STEPB(C2); STEPQ(A3); STEPB(C3); \
    LDF(A0,(o_)+8); LDF(A1,(o_)+9); LDF(A2,(o_)+10); LDF(A3,(o_)+11); \
    LDFB(C0,(o_)+8); LDFB(C1,(o_)+9); LDFB(C2,(o_)+10); LDFB(C3,(o_)+11); \
    STEPQ(B0); STEPB(D0); STEPQ(B1); STEPB(D1); \
    STEPQ(B2); STEPB(D2); STEPQ(B3); STEPB(D3); \
    LDF(B0,(o_)+12); LDF(B1,(o_)+13); LDF(B2,(o_)+14); LDF(B3,(o_)+15); \
    LDFB(D0,(o_)+12); LDFB(D1,(o_)+13); LDFB(D2,(o_)+14); LDFB(D3,(o_)+15); \
    STEPQ(A0); STEPB(C0); STEPQ(A1); STEPB(C1); \
    STEPQ(A2); STEPB(C2); STEPQ(A3); STEPB(C3); \
    STEPQ(B0); STEPB(D0); STEPQ(B1); STEPB(D1); \
    STEPQ(B2); STEPB(D2); STEPQ(B3); STEPB(D3); \
    RESCALE2(); }

    if (wv >= 1) {
        fill_phase(0);
    } else {
        __builtin_amdgcn_s_setprio(1);
        // fwd init (t=0)
        float pb0_ = rowb[BLANK] + 1e-7f;
        float p10_ = rowb[e1]    + 1e-7f;
        a0 = (l == 0) ? 1.0 : 0.0;
        a1 = (l == 0) ? (double)(p10_ / pb0_) : 0.0;
        Lsum = (double)flog2(pb0_);
        // bwd init (indicator at final positions)
        const int llb = lab_len[bb];
        const int pa = 2 * llb, pq = 2 * llb - 1;
        g0 = (4 * l     == pa) ? 1.0 : 0.0;
        g1 = (4 * l + 1 == pq) ? 1.0 : 0.0;
        g2 = (4 * l + 2 == pa) ? 1.0 : 0.0;
        g3 = (4 * l + 3 == pq) ? 1.0 : 0.0;
    }
    __syncthreads();

    for (int ph = 0; ph < P; ++ph) {
        if (wv >= 1) {
            if (ph + 1 < P) fill_phase(ph + 1);
        } else {
            const char* baseF_ = ldsb + (ph & 1) * BUFSZ32;
            const char* baseB_ = ldsb + (2 + (ph & 1)) * BUFSZ32;
            const int stepsF = min(32, Hf - ph * PH);
            const int stepsB = max(0, min(32, Hb - ph * PH));
            if (stepsF == 32 && stepsB == 32) {
                H16(0); H16(16);
            } else {
                for (int k_ = 0; k_ < stepsF; ++k_) {
                    DECLF(Tq);
                    if (k_ < stepsB) {
                        DECLB(Tu);
                        LDF(Tq, k_); LDFB(Tu, k_);
                        STEPQ(Tq); STEPB(Tu);
                    } else {
                        LDF(Tq, k_); STEPQ(Tq);
                    }
                    if (k_ == 15) RESCALE2();
                }
                RESCALE2();
            }
            Lsum += (double)(lgs[ph & 1][0] + lgs[ph & 1][1] +
                             lgs[ph & 1][2] + lgs[ph & 1][3]);
        }
        __syncthreads();
    }

    if (wv == 0) {
        // in-wave combine: loss = -ln( sum_s alpha_H[s] * beta_H[s] )
        double d = a0 * g0 + a1 * g1 + a2 * g2 + a3 * g3;
        d += __shfl_xor(d, 1);  d += __shfl_xor(d, 2);  d += __shfl_xor(d, 4);
        d += __shfl_xor(d, 8);  d += __shfl_xor(d, 16); d += __shfl_xor(d, 32);
        if (l == 0) {
            int hi = __double2hiint(d), lo = __double2loint(d);
            int ke = (hi >> 20) & 0x7FF;
            double mant = __hiloint2double((hi & 0x000FFFFF) | (1023 << 20), lo);
            float r = flog2((float)mant) + (float)(ke - 1023 + E) + (float)Lsum;
            out[bb] = -r * LN2F;
        }
    }
}

extern "C" void kernel_launch(void* const* d_in, const int* in_sizes, int n_in,
                              void* d_out, int out_size, void* d_ws, size_t ws_size,
                              hipStream_t stream) {
    const int*   y_true  = (const int*)d_in[0];
    const float* y_pred  = (const float*)d_in[1];
    const int*   in_len  = (const int*)d_in[2];
    const int*   lab_len = (const int*)d_in[3];
    float*       out     = (float*)d_out;

    ctc_fused_kernel<<<B_, 320, 0, stream>>>(y_true, y_pred, in_len, lab_len, out);
}

// Round 25
// 32.458 us; speedup vs baseline: 1.7967x; 1.7967x over previous
//
#include <hip/hip_runtime.h>

#define B_ 64
#define T_ 1000
#define C_ 128
#define L_ 100
#define BLANK 127     // C-1
#define LN2F 0.69314718055994530942f
#define PH 64
#define NPROD 8
#define FSTRIDE 1024  // 64 lanes * 16B (q1,q3 f64 pair)
#define BUFSZ (PH * FSTRIDE)          // 65536

__device__ __forceinline__ float flog2(float x) { return __builtin_amdgcn_logf(x); }
__device__ __forceinline__ float frcp(float x)  { return __builtin_amdgcn_rcpf(x); }

#define DPP_ROW_SHR1   0x111
#define DPP_ROW_SHR2   0x112
#define DPP_ROW_SHR4   0x114
#define DPP_ROW_SHR8   0x118
#define DPP_WAVE_SHR1  0x138   // lane i <- lane i-1 (validated R8)
#define DPP_WAVE_SHL1  0x130   // lane i <- lane i+1 (validated R15/R16)

template <int CTRL>
__device__ __forceinline__ int dpp_mov(int src) {
    return __builtin_amdgcn_update_dpp(0, src, CTRL, 0xF, 0xF, false);
}

// R25 = R19 exactly (proven best, 32.5us): 128 blocks x 9 waves, PH=64,
// RESCALE cadence 16, separate combine kernel, 4-step-batched tail.
// R23 (composition) and R24 (dual-chain fusion) both regressed: the
// consumer step is issue-bound (~130cy/step), and both added issue.
__global__ __launch_bounds__(576) void ctc_split_kernel(
    const int* __restrict__ y_true, const float* __restrict__ y_pred,
    const int* __restrict__ in_len, const int* __restrict__ lab_len,
    double* __restrict__ AVf, double* __restrict__ AVb,
    double* __restrict__ Ls, int* __restrict__ Es)
{
    const int bb    = blockIdx.x & 63;
    const bool isB  = blockIdx.x >= 64;
    const int tid   = threadIdx.x;
    const int l     = tid & 63;
    const int wv    = tid >> 6;          // 0 = consumer, 1..8 = producers

    __shared__ __align__(16) char ldsb[2 * BUFSZ];
    __shared__ float lgs[2][NPROD];

    const int k1 = min(2 * l, L_ - 1);
    const int k3 = min(2 * l + 1, L_ - 1);
    const int e1 = y_true[bb * L_ + k1];
    const int e3 = y_true[bb * L_ + k3];
    const double m1 = (k1 == 0 || e1 != y_true[bb * L_ + k1 - 1]) ? 1.0 : 0.0;
    const double m3 = (e3 != y_true[bb * L_ + k3 - 1]) ? 1.0 : 0.0;
    const int k1n = min(2 * l + 2, L_ - 1);
    const double m1n = (y_true[bb * L_ + k1n] != y_true[bb * L_ + k1n - 1]) ? 1.0 : 0.0;

    const int Teff = min(T_, in_len[bb]);
    const int N    = Teff - 1;
    const int Hf   = (N + 1) >> 1;
    const int Hb   = N - Hf;
    const int steps_total = isB ? Hb : Hf;
    const int P_full = steps_total >> 6;
    const int rem    = steps_total & 63;
    const int P      = P_full + (rem ? 1 : 0);
    const float* rowb = y_pred + (size_t)bb * T_ * C_;

    double a0 = 0.0, a1 = 0.0, a2 = 0.0, a3 = 0.0;
    double Lsum = 0.0;
    int E = 0;

    const int fs = (wv - 1) * 8;

    auto fillw = [&](int phf) {
        char* bbw = ldsb + (phf & 1) * BUFSZ;
        const int kb_ = phf * PH + fs;
        float g10,g30,gb0, g11,g31,gb1, g12,g32,gb2, g13,g33,gb3,
              g14,g34,gb4, g15,g35,gb5, g16,g36,gb6, g17,g37,gb7;
        int t0_,t1_,t2_,t3_,t4_,t5_,t6_,t7_;
#define FR(i_) (isB ? (N - (kb_ + i_)) : (1 + kb_ + i_))
        t0_=FR(0); t1_=FR(1); t2_=FR(2); t3_=FR(3);
        t4_=FR(4); t5_=FR(5); t6_=FR(6); t7_=FR(7);
#undef FR
        {
            const float* r_;
            r_ = rowb + (size_t)min(max(t0_,1),N) * C_; g10=r_[e1]; g30=r_[e3]; gb0=r_[BLANK];
            r_ = rowb + (size_t)min(max(t1_,1),N) * C_; g11=r_[e1]; g31=r_[e3]; gb1=r_[BLANK];
            r_ = rowb + (size_t)min(max(t2_,1),N) * C_; g12=r_[e1]; g32=r_[e3]; gb2=r_[BLANK];
            r_ = rowb + (size_t)min(max(t3_,1),N) * C_; g13=r_[e1]; g33=r_[e3]; gb3=r_[BLANK];
            r_ = rowb + (size_t)min(max(t4_,1),N) * C_; g14=r_[e1]; g34=r_[e3]; gb4=r_[BLANK];
            r_ = rowb + (size_t)min(max(t5_,1),N) * C_; g15=r_[e1]; g35=r_[e3]; gb5=r_[BLANK];
            r_ = rowb + (size_t)min(max(t6_,1),N) * C_; g16=r_[e1]; g36=r_[e3]; gb6=r_[BLANK];
            r_ = rowb + (size_t)min(max(t7_,1),N) * C_; g17=r_[e1]; g37=r_[e3]; gb7=r_[BLANK];
        }
        __builtin_amdgcn_sched_barrier(0);
        float lgs_ = 0.f;
#define PWR(i_, T_V, G1, G3, GB) { \
        float rb_ = GB + 1e-7f; \
        float rc_ = frcp(rb_); \
        char* q_ = bbw + (fs + i_) * FSTRIDE; \
        *(double2*)(q_ + 16 * l) = make_double2((double)((G1 + 1e-7f) * rc_), \
                                                 (double)((G3 + 1e-7f) * rc_)); \
        bool ok_ = isB ? (T_V >= Hf + 1 && T_V <= N) : (T_V >= 1 && T_V <= Hf); \
        lgs_ += ok_ ? flog2(rb_) : 0.f; }
        PWR(0, t0_, g10, g30, gb0); PWR(1, t1_, g11, g31, gb1);
        PWR(2, t2_, g12, g32, gb2); PWR(3, t3_, g13, g33, gb3);
        PWR(4, t4_, g14, g34, gb4); PWR(5, t5_, g15, g35, gb5);
        PWR(6, t6_, g16, g36, gb6); PWR(7, t7_, g17, g37, gb7);
#undef PWR
        if (l == 0) lgs[phf & 1][wv - 1] = lgs_;
    };

#define DECLF(Pr) double Pr##q1, Pr##q3
#define DECLB(Pr) double Pr##q1, Pr##q3, Pr##q1n
#define LDF(Pr, fi_) { \
    double2 v_ = *(const double2*)(bbp_ + (fi_) * FSTRIDE + 16 * l); \
    Pr##q1 = v_.x; Pr##q3 = v_.y; }
#define LDFB(Pr, fi_) { \
    double2 v_ = *(const double2*)(bbp_ + (fi_) * FSTRIDE + 16 * l); \
    Pr##q1 = v_.x; Pr##q3 = v_.y; \
    Pr##q1n = *(const double*)(bbp_ + (fi_) * FSTRIDE + 16 * ((l + 1) & 63)); }

#define STEPQ(Pr) { \
    int slo_ = dpp_mov<DPP_WAVE_SHR1>(__double2loint(a3)); \
    int shi_ = dpp_mov<DPP_WAVE_SHR1>(__double2hiint(a3)); \
    double pm1_ = __hiloint2double(shi_, slo_); \
    double n0_ = a0 + pm1_; \
    double n1_ = (a1 + a0 + m1 * pm1_) * Pr##q1; \
    double n2_ = a2 + a1; \
    double n3_ = (a3 + a2 + m3 * a1) * Pr##q3; \
    a0 = n0_; a1 = n1_; a2 = n2_; a3 = n3_; }

#define STEPB(Pr) { \
    int n0lo_ = dpp_mov<DPP_WAVE_SHL1>(__double2loint(a0)); \
    int n0hi_ = dpp_mov<DPP_WAVE_SHL1>(__double2hiint(a0)); \
    int n1lo_ = dpp_mov<DPP_WAVE_SHL1>(__double2loint(a1)); \
    int n1hi_ = dpp_mov<DPP_WAVE_SHL1>(__double2hiint(a1)); \
    double b0n_ = __hiloint2double(n0hi_, n0lo_); \
    double b1n_ = __hiloint2double(n1hi_, n1lo_); \
    double c1_ = a1 * Pr##q1; \
    double c3_ = a3 * Pr##q3; \
    double c1n_ = b1n_ * Pr##q1n; \
    double n0_ = a0 + c1_; \
    double n1_ = c1_ + a2 + m3 * c3_; \
    double n2_ = a2 + c3_; \
    double n3_ = c3_ + b0n_ + m1n * c1n_; \
    a0 = n0_; a1 = n1_; a2 = n2_; a3 = n3_; }

#define DPPMAX(u_, ctrl_) { unsigned t_ = (unsigned)dpp_mov<ctrl_>((int)(u_)); \
    u_ = max(u_, t_); }
#define RESCALE() { \
    unsigned u_ = max(max((unsigned)__double2hiint(a0), (unsigned)__double2hiint(a1)), \
                      max((unsigned)__double2hiint(a2), (unsigned)__double2hiint(a3))); \
    DPPMAX(u_, DPP_ROW_SHR1); \
    DPPMAX(u_, DPP_ROW_SHR2); \
    DPPMAX(u_, DPP_ROW_SHR4); \
    DPPMAX(u_, DPP_ROW_SHR8); \
    unsigned g_ = max(max((unsigned)__builtin_amdgcn_readlane((int)u_, 15), \
                          (unsigned)__builtin_amdgcn_readlane((int)u_, 31)), \
                      max((unsigned)__builtin_amdgcn_readlane((int)u_, 47), \
                          (unsigned)__builtin_amdgcn_readlane((int)u_, 63))); \
    int kk_ = (int)(g_ >> 20); \
    if (kk_ > 0) { \
        double f_ = __hiloint2double((2046 - kk_) << 20, 0); \
        a0 *= f_; a1 *= f_; a2 *= f_; a3 *= f_; \
        E += kk_ - 1023; } }

// validated 32-step bodies (2 RESCALEs, cadence 16)
#define BODY32F(base_) { \
    const char* bbp_ = (base_); \
    DECLF(A0); DECLF(A1); DECLF(A2); DECLF(A3); \
    DECLF(B0); DECLF(B1); DECLF(B2); DECLF(B3); \
    LDF(A0,0); LDF(A1,1); LDF(A2,2); LDF(A3,3); \
    LDF(B0,4); LDF(B1,5); LDF(B2,6); LDF(B3,7); \
    STEPQ(A0); STEPQ(A1); STEPQ(A2); STEPQ(A3); \
    LDF(A0,8); LDF(A1,9); LDF(A2,10); LDF(A3,11); \
    STEPQ(B0); STEPQ(B1); STEPQ(B2); STEPQ(B3); \
    LDF(B0,12); LDF(B1,13); LDF(B2,14); LDF(B3,15); \
    STEPQ(A0); STEPQ(A1); STEPQ(A2); STEPQ(A3); \
    LDF(A0,16); LDF(A1,17); LDF(A2,18); LDF(A3,19); \
    STEPQ(B0); STEPQ(B1); STEPQ(B2); STEPQ(B3); RESCALE(); \
    LDF(B0,20); LDF(B1,21); LDF(B2,22); LDF(B3,23); \
    STEPQ(A0); STEPQ(A1); STEPQ(A2); STEPQ(A3); \
    LDF(A0,24); LDF(A1,25); LDF(A2,26); LDF(A3,27); \
    STEPQ(B0); STEPQ(B1); STEPQ(B2); STEPQ(B3); \
    LDF(B0,28); LDF(B1,29); LDF(B2,30); LDF(B3,31); \
    STEPQ(A0); STEPQ(A1); STEPQ(A2); STEPQ(A3); \
    STEPQ(B0); STEPQ(B1); STEPQ(B2); STEPQ(B3); RESCALE(); }

#define BODY32B(base_) { \
    const char* bbp_ = (base_); \
    DECLB(A0); DECLB(A1); DECLB(A2); DECLB(A3); \
    DECLB(B0); DECLB(B1); DECLB(B2); DECLB(B3); \
    LDFB(A0,0); LDFB(A1,1); LDFB(A2,2); LDFB(A3,3); \
    LDFB(B0,4); LDFB(B1,5); LDFB(B2,6); LDFB(B3,7); \
    STEPB(A0); STEPB(A1); STEPB(A2); STEPB(A3); \
    LDFB(A0,8); LDFB(A1,9); LDFB(A2,10); LDFB(A3,11); \
    STEPB(B0); STEPB(B1); STEPB(B2); STEPB(B3); \
    LDFB(B0,12); LDFB(B1,13); LDFB(B2,14); LDFB(B3,15); \
    STEPB(A0); STEPB(A1); STEPB(A2); STEPB(A3); \
    LDFB(A0,16); LDFB(A1,17); LDFB(A2,18); LDFB(A3,19); \
    STEPB(B0); STEPB(B1); STEPB(B2); STEPB(B3); RESCALE(); \
    LDFB(B0,20); LDFB(B1,21); LDFB(B2,22); LDFB(B3,23); \
    STEPB(A0); STEPB(A1); STEPB(A2); STEPB(A3); \
    LDFB(A0,24); LDFB(A1,25); LDFB(A2,26); LDFB(A3,27); \
    STEPB(B0); STEPB(B1); STEPB(B2); STEPB(B3); \
    LDFB(B0,28); LDFB(B1,29); LDFB(B2,30); LDFB(B3,31); \
    STEPB(A0); STEPB(A1); STEPB(A2); STEPB(A3); \
    STEPB(B0); STEPB(B1); STEPB(B2); STEPB(B3); RESCALE(); }

    if (wv >= 1) {
        fillw(0);
    } else if (!isB) {
        __builtin_amdgcn_s_setprio(1);
        float pb0_ = rowb[BLANK] + 1e-7f;
        float p10_ = rowb[e1]    + 1e-7f;
        a0 = (l == 0) ? 1.0 : 0.0;
        a1 = (l == 0) ? (double)(p10_ / pb0_) : 0.0;
        Lsum = (double)flog2(pb0_);
    } else {
        __builtin_amdgcn_s_setprio(1);
        const int llb = lab_len[bb];
        const int pa = 2 * llb, pq = 2 * llb - 1;
        a0 = (4 * l     == pa) ? 1.0 : 0.0;
        a1 = (4 * l + 1 == pq) ? 1.0 : 0.0;
        a2 = (4 * l + 2 == pa) ? 1.0 : 0.0;
        a3 = (4 * l + 3 == pq) ? 1.0 : 0.0;
    }
    __syncthreads();

    for (int ph = 0; ph < P; ++ph) {
        if (wv >= 1) {
            if (ph + 1 < P) fillw(ph + 1);
        } else {
            const char* base_ = ldsb + (ph & 1) * BUFSZ;
            const int steps = (ph < P_full) ? 64 : rem;
            if (steps == 64) {
                if (!isB) { BODY32F(base_); BODY32F(base_ + 32 * FSTRIDE); }
                else      { BODY32B(base_); BODY32B(base_ + 32 * FSTRIDE); }
            } else {
                const char* bbp_ = base_;
                int k_ = 0;
                if (!isB) {
                    for (; k_ + 4 <= steps; k_ += 4) {
                        DECLF(T0); DECLF(T1); DECLF(T2); DECLF(T3);
                        LDF(T0, k_); LDF(T1, k_ + 1); LDF(T2, k_ + 2); LDF(T3, k_ + 3);
                        STEPQ(T0); STEPQ(T1); STEPQ(T2); STEPQ(T3);
                        if ((k_ & 15) == 12) RESCALE();
                    }
                    for (; k_ < steps; ++k_) {
                        DECLF(Tq); LDF(Tq, k_); STEPQ(Tq);
                    }
                } else {
                    for (; k_ + 4 <= steps; k_ += 4) {
                        DECLB(T0); DECLB(T1); DECLB(T2); DECLB(T3);
                        LDFB(T0, k_); LDFB(T1, k_ + 1); LDFB(T2, k_ + 2); LDFB(T3, k_ + 3);
                        STEPB(T0); STEPB(T1); STEPB(T2); STEPB(T3);
                        if ((k_ & 15) == 12) RESCALE();
                    }
                    for (; k_ < steps; ++k_) {
                        DECLB(Tq); LDFB(Tq, k_); STEPB(Tq);
                    }
                }
                RESCALE();
            }
            float lg_ = 0.f;
            #pragma unroll
            for (int w_ = 0; w_ < NPROD; ++w_) lg_ += lgs[ph & 1][w_];
            Lsum += (double)lg_;
        }
        __syncthreads();
    }

    if (wv == 0) {
        double* AV = (isB ? AVb : AVf) + bb * 256;
        AV[4 * l + 0] = a0; AV[4 * l + 1] = a1;
        AV[4 * l + 2] = a2; AV[4 * l + 3] = a3;
        if (l == 0) {
            Ls[bb * 2 + (isB ? 1 : 0)] = Lsum;
            Es[bb * 2 + (isB ? 1 : 0)] = E;
        }
    }
}

__global__ __launch_bounds__(64) void ctc_combine_kernel(
    const double* __restrict__ AVf, const double* __restrict__ AVb,
    const double* __restrict__ Ls, const int* __restrict__ Es,
    float* __restrict__ out)
{
    const int b = blockIdx.x;
    const int l = threadIdx.x;
    const double* f = AVf + b * 256;
    const double* g = AVb + b * 256;
    double d = f[4*l+0]*g[4*l+0] + f[4*l+1]*g[4*l+1]
             + f[4*l+2]*g[4*l+2] + f[4*l+3]*g[4*l+3];
    d += __shfl_xor(d, 1);  d += __shfl_xor(d, 2);  d += __shfl_xor(d, 4);
    d += __shfl_xor(d, 8);  d += __shfl_xor(d, 16); d += __shfl_xor(d, 32);
    if (l == 0) {
        double Ltot = Ls[b * 2] + Ls[b * 2 + 1];
        int    Etot = Es[b * 2] + Es[b * 2 + 1];
        int hi = __double2hiint(d), lo = __double2loint(d);
        int ke = (hi >> 20) & 0x7FF;
        double mant = __hiloint2double((hi & 0x000FFFFF) | (1023 << 20), lo);
        float r = flog2((float)mant) + (float)(ke - 1023 + Etot) + (float)Ltot;
        out[b] = -r * LN2F;
    }
}

extern "C" void kernel_launch(void* const* d_in, const int* in_sizes, int n_in,
                              void* d_out, int out_size, void* d_ws, size_t ws_size,
                              hipStream_t stream) {
    const int*   y_true  = (const int*)d_in[0];
    const float* y_pred  = (const float*)d_in[1];
    const int*   in_len  = (const int*)d_in[2];
    const int*   lab_len = (const int*)d_in[3];
    float*       out     = (float*)d_out;

    double* AVf = (double*)d_ws;                 // [64][256]
    double* AVb = AVf + 64 * 256;                // [64][256]
    double* Ls  = AVb + 64 * 256;                // [64][2]
    int*    Es  = (int*)(Ls + 128);              // [64][2]

    ctc_split_kernel<<<128, 576, 0, stream>>>(y_true, y_pred, in_len, lab_len,
                                              AVf, AVb, Ls, Es);
    ctc_combine_kernel<<<64, 64, 0, stream>>>(AVf, AVb, Ls, Es, out);
}